// Round 17
// baseline (929.073 us; speedup 1.0000x reference)
//
#include <hip/hip_runtime.h>
#include <hip/hip_bf16.h>
#include <math.h>

// Problem constants
#define NT 32768
#define HD 96
#define DEG 8
#define NE (NT * DEG)
#define LRELU_ALPHA 0.2f
#define CH 16384             // GRU row-chunk

typedef __attribute__((ext_vector_type(8))) short bf16x8;     // 8 bf16 (4 VGPRs)
typedef __attribute__((ext_vector_type(8))) unsigned short u16x8;
typedef __attribute__((ext_vector_type(4))) unsigned short u16x4;
typedef __attribute__((ext_vector_type(4))) float f32x4;

__device__ __forceinline__ unsigned short f2bf(float x) {
    union { float f; unsigned u; } v; v.f = x;
    unsigned r = v.u + 0x7FFFu + ((v.u >> 16) & 1u);   // RNE
    return (unsigned short)(r >> 16);
}
__device__ __forceinline__ float bf2f(unsigned short u) {
    union { unsigned u; float f; } v; v.u = ((unsigned)u) << 16; return v.f;
}

__device__ __forceinline__ void gload_lds16(const void* g, void* l) {
    __builtin_amdgcn_global_load_lds(
        (const __attribute__((address_space(1))) void*)g,
        (__attribute__((address_space(3))) void*)l, 16, 0, 0);
}

// ---------------------------------------------------------------------------
// Pack kernels
// ---------------------------------------------------------------------------

// W [H,768,96] f32 -> T bf16 [768 c][768 f], T[c][f] = W[c/96][f][c%96]
__global__ void packWT(const float* __restrict__ W, unsigned short* __restrict__ T) {
    int idx = blockIdx.x * 256 + threadIdx.x;
    if (idx >= 768 * 768) return;
    int c = idx / 768, f = idx % 768;
    T[idx] = f2bf(W[(size_t)(c / HD) * 768 * HD + (size_t)f * HD + (c % HD)]);
}

// vectorized f32 -> bf16 (8 elems/thread); n8 = n/8
__global__ void cvt_bf8(const float* __restrict__ X, unsigned short* __restrict__ Y, int n8) {
    int i = blockIdx.x * 256 + threadIdx.x;
    if (i >= n8) return;
    float4 a = ((const float4*)X)[2 * i];
    float4 b = ((const float4*)X)[2 * i + 1];
    u16x8 p;
    p[0] = f2bf(a.x); p[1] = f2bf(a.y); p[2] = f2bf(a.z); p[3] = f2bf(a.w);
    p[4] = f2bf(b.x); p[5] = f2bf(b.y); p[6] = f2bf(b.z); p[7] = f2bf(b.w);
    ((u16x8*)Y)[i] = p;
}

// Fold Wx against ax_dst, TRANSPOSED: wvT[f*8+h] = sum_d Wx[h][f][d]*ax[h][96+d];
// cd[h] = sum_d bx[h][d]*ax[h][96+d]
__global__ void packWVT(const float* __restrict__ Wx, const float* __restrict__ ax,
                        const float* __restrict__ bx,
                        float* __restrict__ wvT, float* __restrict__ cd) {
    int idx = blockIdx.x * 256 + threadIdx.x;
    if (idx < 8 * 768) {
        int h = idx / 768, f = idx % 768;
        const float* wp = Wx + (size_t)h * 768 * HD + (size_t)f * HD;
        const float* ap = ax + h * 2 * HD + HD;
        float s = 0.f;
        for (int d = 0; d < HD; d++) s += wp[d] * ap[d];
        wvT[(size_t)f * 8 + h] = s;
    }
    if (idx < 8) {
        const float* bp = bx + idx * HD;
        const float* ap = ax + idx * 2 * HD + HD;
        float s = 0.f;
        for (int d = 0; d < HD; d++) s += bp[d] * ap[d];
        cd[idx] = s;
    }
}

// ---------------------------------------------------------------------------
// Dual-source bf16 MFMA GEMM (round-10/13 proven): 128x128, BK=32, 256 thr
// (4 waves 2x2), 4 blocks/CU, dbuf LDS, one barrier per K-step, XOR source
// preswizzle (slot s holds k-word s^((r>>1)&3)), XCD-aware tile swizzle.
// Used for BOTH the merged projection (A2 spans [hbc;hbs] rows) and GRU.
// ---------------------------------------------------------------------------
__global__ __launch_bounds__(256, 4) void mgemm2(
    const unsigned short* __restrict__ A1, const unsigned short* __restrict__ A2,
    const unsigned short* __restrict__ BT1, const unsigned short* __restrict__ BT2,
    const float* __restrict__ bias1, const float* __restrict__ bias2,
    unsigned short* __restrict__ C1, unsigned short* __restrict__ C2,
    int mt1, int N, int K) {
    __shared__ unsigned short Alds[2][128 * 32];
    __shared__ unsigned short Blds[2][128 * 32];
    const int tid = threadIdx.x;
    const int w = tid >> 6, l = tid & 63;
    const int wr = w >> 1, wc = w & 1;
    const int lrow = l & 15, lk = l >> 4;

    const int nx = gridDim.x;
    const int nwg = nx * gridDim.y;
    int lin = blockIdx.y * nx + blockIdx.x;
    if ((nwg & 7) == 0) lin = (lin & 7) * (nwg >> 3) + (lin >> 3);
    int bm = lin / nx;
    const int bn = lin % nx;

    const bool p1 = bm < mt1;
    const unsigned short* A  = p1 ? A1 : A2;
    const unsigned short* BT = p1 ? BT1 : BT2;
    const float* bias        = p1 ? bias1 : bias2;
    unsigned short* C        = p1 ? C1 : C2;
    if (!p1) bm -= mt1;

    const unsigned short* asrc[2];
    const unsigned short* bsrc[2];
    #pragma unroll
    for (int q = 0; q < 2; q++) {
        int idx = q * 256 + tid;
        int r = idx >> 2, s = idx & 3;
        int kw = s ^ ((r >> 1) & 3);
        asrc[q] = A  + (size_t)(bm * 128 + r) * K + kw * 8;
        bsrc[q] = BT + (size_t)(bn * 128 + r) * K + kw * 8;
    }
    const int ldst = (w * 64) * 8;

    gload_lds16(asrc[0], &Alds[0][ldst]);
    gload_lds16(asrc[1], &Alds[0][2048 + ldst]);
    gload_lds16(bsrc[0], &Blds[0][ldst]);
    gload_lds16(bsrc[1], &Blds[0][2048 + ldst]);

    f32x4 acc[4][4] = {};
    const int nt = K >> 5;

    for (int t = 0; t < nt; ++t) {
        const int cur = t & 1;
        __syncthreads();
        if (t + 1 < nt) {
            const int k1 = (t + 1) << 5;
            gload_lds16(asrc[0] + k1, &Alds[cur ^ 1][ldst]);
            gload_lds16(asrc[1] + k1, &Alds[cur ^ 1][2048 + ldst]);
            gload_lds16(bsrc[0] + k1, &Blds[cur ^ 1][ldst]);
            gload_lds16(bsrc[1] + k1, &Blds[cur ^ 1][2048 + ldst]);
        }
        bf16x8 af[4], bfv[4];
        #pragma unroll
        for (int i = 0; i < 4; i++) {
            int r = wr * 64 + i * 16 + lrow;
            int s = lk ^ ((r >> 1) & 3);
            af[i] = *(const bf16x8*)(&Alds[cur][r * 32 + s * 8]);
        }
        #pragma unroll
        for (int j = 0; j < 4; j++) {
            int r = wc * 64 + j * 16 + lrow;
            int s = lk ^ ((r >> 1) & 3);
            bfv[j] = *(const bf16x8*)(&Blds[cur][r * 32 + s * 8]);
        }
        #pragma unroll
        for (int i = 0; i < 4; i++)
            #pragma unroll
            for (int j = 0; j < 4; j++)
                acc[i][j] = __builtin_amdgcn_mfma_f32_16x16x32_bf16(af[i], bfv[j], acc[i][j], 0, 0, 0);
    }

    const size_t crow0 = (size_t)bm * 128 + wr * 64;
    const int ccol0 = bn * 128 + wc * 64;
    #pragma unroll
    for (int j = 0; j < 4; j++) {
        int col = ccol0 + j * 16 + lrow;
        float bv = bias[col];
        #pragma unroll
        for (int i = 0; i < 4; i++) {
            size_t row = crow0 + i * 16 + lk * 4;
            #pragma unroll
            for (int e = 0; e < 4; e++)
                C[(row + e) * N + col] = f2bf(acc[i][j][e] + bv);
        }
    }
}

// ---------------------------------------------------------------------------
// Merged edge-score dispatch: blocks [0, NE/256) compute the intra dual
// scores over Xd (Hdb); blocks [NE/256, 3NE/256) compute single src scores
// over Xs (Pcat, 2NT rows).
// ---------------------------------------------------------------------------
__global__ __launch_bounds__(256) void escore_all(
    const unsigned short* __restrict__ Xd, const unsigned short* __restrict__ Xs,
    const float* __restrict__ ag, const float* __restrict__ ax,
    float* __restrict__ s0out, float* __restrict__ s1out,
    float* __restrict__ sout) {
    __shared__ float av0[768], av1[768], axs[768];
    for (int t = threadIdx.x; t < 768; t += 256) {
        int hh = t / HD, d = t % HD;
        av0[t] = ag[hh * 2 * HD + d];
        av1[t] = ag[hh * 2 * HD + HD + d];
        axs[t] = ax[hh * 2 * HD + d];
    }
    __syncthreads();
    const int NB0 = NE / 256;
    if ((int)blockIdx.x < NB0) {
        int idx = blockIdx.x * 256 + threadIdx.x;
        int row = idx >> 3, hh = idx & 7;
        const unsigned short* xp = Xd + (size_t)row * 768 + hh * HD;
        const float* a0 = av0 + hh * HD;
        const float* a1 = av1 + hh * HD;
        float s0 = 0.f, s1 = 0.f;
        #pragma unroll
        for (int q = 0; q < 12; q++) {
            u16x8 v = *(const u16x8*)(xp + q * 8);
            #pragma unroll
            for (int e = 0; e < 8; e++) {
                float x = bf2f(v[e]);
                s0 += x * a0[q * 8 + e];
                s1 += x * a1[q * 8 + e];
            }
        }
        s0out[idx] = s0;
        s1out[idx] = s1;
    } else {
        int idx = (blockIdx.x - NB0) * 256 + threadIdx.x;   // over 2NE
        int row = idx >> 3, hh = idx & 7;
        const unsigned short* xp = Xs + (size_t)row * 768 + hh * HD;
        const float* ap = axs + hh * HD;
        float s = 0.f;
        #pragma unroll
        for (int q = 0; q < 12; q++) {
            u16x8 v = *(const u16x8*)(xp + q * 8);
            #pragma unroll
            for (int e = 0; e < 8; e++) s += bf2f(v[e]) * ap[q * 8 + e];
        }
        sout[idx] = s;
    }
}

// ---------------------------------------------------------------------------
// Per-dst softmax + aggregate (intra), one WAVE per dst segment, PLUS fused
// folded dst-score: ED[dnode,h] = sum_c X[dnode,c]*wvT[c][h] + cd[h],
// computed from the in-register f32 outputs. (round-14 proven)
// ---------------------------------------------------------------------------
__global__ __launch_bounds__(256) void attend_agg(
    const unsigned short* __restrict__ Whs, const float* __restrict__ es,
    const float* __restrict__ ed, const float* __restrict__ ab,
    const int* __restrict__ src, const int* __restrict__ dst,
    unsigned short* __restrict__ out,
    const float* __restrict__ wvT, const float* __restrict__ cd,
    float* __restrict__ edout) {
    const int wv = threadIdx.x >> 6, l = threadIdx.x & 63;
    const int seg = blockIdx.x * 4 + wv;
    const int hh = l >> 3, j = l & 7;
    int sj = src[seg * 8 + j];
    int dnode = dst[seg * 8];
    float e = es[(size_t)sj * 8 + hh] + ed[(size_t)dnode * 8 + hh] + ab[hh];
    e = e > 0.f ? e : LRELU_ALPHA * e;
    float m = e;
    #pragma unroll
    for (int o = 1; o < 8; o <<= 1) m = fmaxf(m, __shfl_xor(m, o, 64));
    float ex = expf(e - m);
    float s = ex;
    #pragma unroll
    for (int o = 1; o < 8; o <<= 1) s += __shfl_xor(s, o, 64);
    float att = ex / s;

    float p8[8] = {};
    #pragma unroll
    for (int u = 0; u < 3; u++) {
        int c = 4 * l + 256 * u;
        int h = c / HD;
        float acc0 = 0.f, acc1 = 0.f, acc2 = 0.f, acc3 = 0.f;
        #pragma unroll
        for (int j2 = 0; j2 < 8; j2++) {
            float a = __shfl(att, h * 8 + j2, 64);
            int sid = __shfl(sj, j2, 64);
            u16x4 v = *(const u16x4*)(Whs + (size_t)sid * 768 + c);
            acc0 += a * bf2f(v[0]); acc1 += a * bf2f(v[1]);
            acc2 += a * bf2f(v[2]); acc3 += a * bf2f(v[3]);
        }
        u16x4 r;
        r[0] = f2bf(acc0); r[1] = f2bf(acc1); r[2] = f2bf(acc2); r[3] = f2bf(acc3);
        *(u16x4*)(out + (size_t)dnode * 768 + c) = r;
        float xs[4] = {acc0, acc1, acc2, acc3};
        #pragma unroll
        for (int jj = 0; jj < 4; jj++) {
            const float* wp = wvT + (size_t)(c + jj) * 8;
            float4 w0 = *(const float4*)wp;
            float4 w1 = *(const float4*)(wp + 4);
            p8[0] += xs[jj] * w0.x; p8[1] += xs[jj] * w0.y;
            p8[2] += xs[jj] * w0.z; p8[3] += xs[jj] * w0.w;
            p8[4] += xs[jj] * w1.x; p8[5] += xs[jj] * w1.y;
            p8[6] += xs[jj] * w1.z; p8[7] += xs[jj] * w1.w;
        }
    }
    #pragma unroll
    for (int o = 1; o < 64; o <<= 1) {
        #pragma unroll
        for (int k = 0; k < 8; k++) p8[k] += __shfl_xor(p8[k], o, 64);
    }
    if (l == 0) {
        float4 c0 = *(const float4*)cd;
        float4 c1 = *(const float4*)(cd + 4);
        float* op = edout + (size_t)dnode * 8;
        *(float4*)op       = make_float4(p8[0] + c0.x, p8[1] + c0.y, p8[2] + c0.z, p8[3] + c0.w);
        *(float4*)(op + 4) = make_float4(p8[4] + c1.x, p8[5] + c1.y, p8[6] + c1.z, p8[7] + c1.w);
    }
}

// ---------------------------------------------------------------------------
// Fused counter+support attend: Hd = 0.5*attend(Wc, esC) + 0.5*attend(Ws, esS).
// ---------------------------------------------------------------------------
__global__ __launch_bounds__(256) void attend2(
    const unsigned short* __restrict__ Wc, const unsigned short* __restrict__ Ws,
    const float* __restrict__ esC, const float* __restrict__ esS,
    const float* __restrict__ ed, const float* __restrict__ ab,
    const int* __restrict__ csrc, const int* __restrict__ ssrc,
    const int* __restrict__ dst, unsigned short* __restrict__ outH) {
    const int wv = threadIdx.x >> 6, l = threadIdx.x & 63;
    const int seg = blockIdx.x * 4 + wv;
    const int hh = l >> 3, j = l & 7;
    int cj = csrc[seg * 8 + j];
    int sj = ssrc[seg * 8 + j];
    int dnode = dst[seg * 8];
    float edv = ed[(size_t)dnode * 8 + hh] + ab[hh];

    float eC = esC[(size_t)cj * 8 + hh] + edv;
    eC = eC > 0.f ? eC : LRELU_ALPHA * eC;
    float mC = eC;
    #pragma unroll
    for (int o = 1; o < 8; o <<= 1) mC = fmaxf(mC, __shfl_xor(mC, o, 64));
    float exC = expf(eC - mC);
    float sC = exC;
    #pragma unroll
    for (int o = 1; o < 8; o <<= 1) sC += __shfl_xor(sC, o, 64);
    float attC = exC / sC;

    float eS = esS[(size_t)sj * 8 + hh] + edv;
    eS = eS > 0.f ? eS : LRELU_ALPHA * eS;
    float mS = eS;
    #pragma unroll
    for (int o = 1; o < 8; o <<= 1) mS = fmaxf(mS, __shfl_xor(mS, o, 64));
    float exS = expf(eS - mS);
    float sS = exS;
    #pragma unroll
    for (int o = 1; o < 8; o <<= 1) sS += __shfl_xor(sS, o, 64);
    float attS = exS / sS;

    #pragma unroll
    for (int u = 0; u < 3; u++) {
        int c = 4 * l + 256 * u;
        int h = c / HD;
        float acc0 = 0.f, acc1 = 0.f, acc2 = 0.f, acc3 = 0.f;
        #pragma unroll
        for (int j2 = 0; j2 < 8; j2++) {
            float a = __shfl(attC, h * 8 + j2, 64);
            int sid = __shfl(cj, j2, 64);
            u16x4 v = *(const u16x4*)(Wc + (size_t)sid * 768 + c);
            acc0 += a * bf2f(v[0]); acc1 += a * bf2f(v[1]);
            acc2 += a * bf2f(v[2]); acc3 += a * bf2f(v[3]);
        }
        #pragma unroll
        for (int j2 = 0; j2 < 8; j2++) {
            float a = __shfl(attS, h * 8 + j2, 64);
            int sid = __shfl(sj, j2, 64);
            u16x4 v = *(const u16x4*)(Ws + (size_t)sid * 768 + c);
            acc0 += a * bf2f(v[0]); acc1 += a * bf2f(v[1]);
            acc2 += a * bf2f(v[2]); acc3 += a * bf2f(v[3]);
        }
        u16x4 r;
        r[0] = f2bf(0.5f * acc0); r[1] = f2bf(0.5f * acc1);
        r[2] = f2bf(0.5f * acc2); r[3] = f2bf(0.5f * acc3);
        *(u16x4*)(outH + (size_t)dnode * 768 + c) = r;
    }
}

// ---------------------------------------------------------------------------
// GRU elementwise tail (bf16 gi/gh/hid, f32 out), 8 cols/thread.
// ---------------------------------------------------------------------------
__global__ __launch_bounds__(256) void gru_elem(
    const unsigned short* __restrict__ gi, const unsigned short* __restrict__ gh,
    const unsigned short* __restrict__ hid, float* __restrict__ out) {
    int idx = blockIdx.x * 256 + threadIdx.x;   // over rows*96
    int nrow = idx / 96, c8 = (idx % 96) * 8;
    const unsigned short* gip = gi + (size_t)nrow * 2304 + c8;
    const unsigned short* ghp = gh + (size_t)nrow * 2304 + c8;
    u16x8 vir = *(const u16x8*)(gip);
    u16x8 viz = *(const u16x8*)(gip + 768);
    u16x8 vin = *(const u16x8*)(gip + 1536);
    u16x8 vhr = *(const u16x8*)(ghp);
    u16x8 vhz = *(const u16x8*)(ghp + 768);
    u16x8 vhn = *(const u16x8*)(ghp + 1536);
    u16x8 vh  = *(const u16x8*)(hid + (size_t)nrow * 768 + c8);
    float res[8];
    #pragma unroll
    for (int e = 0; e < 8; e++) {
        float r = 1.f / (1.f + expf(-(bf2f(vir[e]) + bf2f(vhr[e]))));
        float z = 1.f / (1.f + expf(-(bf2f(viz[e]) + bf2f(vhz[e]))));
        float cand = tanhf(bf2f(vin[e]) + r * bf2f(vhn[e]));
        res[e] = (1.f - z) * cand + z * bf2f(vh[e]);
    }
    float* op = out + (size_t)nrow * 768 + c8;
    *(float4*)(op)     = make_float4(res[0], res[1], res[2], res[3]);
    *(float4*)(op + 4) = make_float4(res[4], res[5], res[6], res[7]);
}

// ---------------------------------------------------------------------------
// Launch. ws (bf16 elems): Xb[SZ] | Hdb[SZ] | GIb[CH*2304] | GHb[CH*2304] |
//   W2gT W2xT WihB WhhB | f32: EScat[2NE] ED ESI EDI WVT[6144] CD[8].
// AB3 ([h|hbc|hbs] bf16 cvt buffer, 3SZ) aliases GIb+GHb exactly.
// Pcat ([2NT,768] bf16 proj scratch) = d_out. Wh lives in Hdb until attend2.
// ---------------------------------------------------------------------------
extern "C" void kernel_launch(void* const* d_in, const int* in_sizes, int n_in,
                              void* d_out, int out_size, void* d_ws, size_t ws_size,
                              hipStream_t stream) {
    const float* h    = (const float*)d_in[0];
    const float* hbc  = (const float*)d_in[1];
    const float* hbs  = (const float*)d_in[2];
    const float* Wg   = (const float*)d_in[3];
    const float* bg   = (const float*)d_in[4];
    const float* ag   = (const float*)d_in[5];
    const float* agb  = (const float*)d_in[6];
    const float* Wx   = (const float*)d_in[7];
    const float* bx   = (const float*)d_in[8];
    const float* ax   = (const float*)d_in[9];
    const float* axb  = (const float*)d_in[10];
    const float* Wih  = (const float*)d_in[11];
    const float* Whh  = (const float*)d_in[12];
    const float* bih  = (const float*)d_in[13];
    const float* bhh  = (const float*)d_in[14];
    const int* i_src  = (const int*)d_in[15];
    const int* i_dst  = (const int*)d_in[16];
    const int* c_src  = (const int*)d_in[17];
    const int* c_dst  = (const int*)d_in[18];
    const int* s_src  = (const int*)d_in[19];
    const int* s_dst  = (const int*)d_in[20];
    float* out = (float*)d_out;

    const size_t SZ = (size_t)NT * 768;
    unsigned short* Xb   = (unsigned short*)d_ws;
    unsigned short* Hdb  = Xb + SZ;
    unsigned short* GIb  = Hdb + SZ;
    unsigned short* GHb  = GIb + (size_t)CH * 2304;
    unsigned short* ABh  = GIb;                      // transient cvt region [3NT,768]
    unsigned short* ABc  = GIb + SZ;
    unsigned short* ABs  = GIb + 2 * SZ;
    unsigned short* W2gT = GHb + (size_t)CH * 2304;
    unsigned short* W2xT = W2gT + 768 * 768;
    unsigned short* WihB = W2xT + 768 * 768;
    unsigned short* WhhB = WihB + 2304 * 768;
    float* EScat = (float*)(WhhB + 2304 * 768);      // [2NE]
    float* ED    = EScat + 2 * NE;
    float* ESI   = ED + NE;
    float* EDI   = ESI + NE;
    float* WVT   = EDI + NE;                         // [768*8]
    float* CD    = WVT + 768 * 8;                    // [8]
    unsigned short* Pcat = (unsigned short*)d_out;   // [2NT,768] bf16 scratch

    dim3 blk(256);
    packWT<<<(768 * 768 + 255) / 256, blk, 0, stream>>>(Wg, W2gT);
    packWT<<<(768 * 768 + 255) / 256, blk, 0, stream>>>(Wx, W2xT);
    cvt_bf8<<<(2304 * 768 / 8 + 255) / 256, blk, 0, stream>>>(Wih, WihB, 2304 * 768 / 8);
    cvt_bf8<<<(2304 * 768 / 8 + 255) / 256, blk, 0, stream>>>(Whh, WhhB, 2304 * 768 / 8);
    packWVT<<<(8 * 768 + 255) / 256, blk, 0, stream>>>(Wx, ax, bx, WVT, CD);

    const int n8 = (int)(SZ / 8);
    const int cvtg = (n8 + 255) / 256;

    // input conversions: [h | hbc | hbs] -> AB3 (bf16)
    cvt_bf8<<<cvtg, blk, 0, stream>>>(h,   ABh, n8);
    cvt_bf8<<<cvtg, blk, 0, stream>>>(hbc, ABc, n8);
    cvt_bf8<<<cvtg, blk, 0, stream>>>(hbs, ABs, n8);

    // 1) merged projection GEMM (one dispatch, 4608 wg, bf16 A):
    //    part1 (256 M-tiles): Wh = h@Wg+bg -> Hdb
    //    part2 (512 M-tiles): [Wc;Ws] = [hbc;hbs]@Wx+bx -> Pcat
    dim3 gproj(6, 768);
    mgemm2<<<gproj, blk, 0, stream>>>(ABh, ABc, W2gT, W2xT, bg, bx,
                                      Hdb, Pcat, 256, 768, 768);
    // 2) all streaming edge scores in ONE dispatch:
    //    intra dual (Hdb -> ESI/EDI) + merged src (Pcat -> EScat[2NE])
    escore_all<<<3 * NE / 256, blk, 0, stream>>>(Hdb, Pcat, ag, ax,
                                                 ESI, EDI, EScat);
    // 3) intra attend -> Xb, with fused folded dst-score -> ED
    attend_agg<<<NT / 4, blk, 0, stream>>>(Hdb, ESI, EDI, agb, i_src, i_dst, Xb,
                                           WVT, CD, ED);
    // 4) fused counter+support attend -> Hdb (Wh dead now)
    attend2<<<NT / 4, blk, 0, stream>>>(Pcat, Pcat + SZ, EScat, EScat + NE, ED, axb,
                                        c_src, s_src, c_dst, Hdb);
    // 5) GRU, row-chunked; gi/gh as ONE dual-source dispatch per chunk
    dim3 ggru(18, 256);
    for (int c0 = 0; c0 < NT; c0 += CH) {
        mgemm2<<<ggru, blk, 0, stream>>>(Xb + (size_t)c0 * 768, Hdb + (size_t)c0 * 768,
                                         WihB, WhhB, bih, bhh, GIb, GHb,
                                         128, 2304, 768);
        gru_elem<<<(CH * 96) / 256, blk, 0, stream>>>(GIb, GHb, Hdb + (size_t)c0 * 768, out + (size_t)c0 * 768);
    }
}

// Round 18
// 901.700 us; speedup vs baseline: 1.0304x; 1.0304x over previous
//
#include <hip/hip_runtime.h>
#include <hip/hip_bf16.h>
#include <math.h>

// Problem constants
#define NT 32768
#define HD 96
#define DEG 8
#define NE (NT * DEG)
#define LRELU_ALPHA 0.2f
#define CH 16384             // GRU row-chunk

typedef __attribute__((ext_vector_type(8))) short bf16x8;     // 8 bf16 (4 VGPRs)
typedef __attribute__((ext_vector_type(8))) unsigned short u16x8;
typedef __attribute__((ext_vector_type(4))) unsigned short u16x4;
typedef __attribute__((ext_vector_type(4))) float f32x4;

__device__ __forceinline__ unsigned short f2bf(float x) {
    union { float f; unsigned u; } v; v.f = x;
    unsigned r = v.u + 0x7FFFu + ((v.u >> 16) & 1u);   // RNE
    return (unsigned short)(r >> 16);
}
__device__ __forceinline__ float bf2f(unsigned short u) {
    union { unsigned u; float f; } v; v.u = ((unsigned)u) << 16; return v.f;
}

__device__ __forceinline__ void gload_lds16(const void* g, void* l) {
    __builtin_amdgcn_global_load_lds(
        (const __attribute__((address_space(1))) void*)g,
        (__attribute__((address_space(3))) void*)l, 16, 0, 0);
}

// ---------------------------------------------------------------------------
// Pack kernels
// ---------------------------------------------------------------------------

// W [H,768,96] f32 -> T bf16 [768 c][768 f], T[c][f] = W[c/96][f][c%96]
__global__ void packWT(const float* __restrict__ W, unsigned short* __restrict__ T) {
    int idx = blockIdx.x * 256 + threadIdx.x;
    if (idx >= 768 * 768) return;
    int c = idx / 768, f = idx % 768;
    T[idx] = f2bf(W[(size_t)(c / HD) * 768 * HD + (size_t)f * HD + (c % HD)]);
}

// vectorized f32 -> bf16 (8 elems/thread); n8 = n/8  (GRU weights)
__global__ void cvt_bf8(const float* __restrict__ X, unsigned short* __restrict__ Y, int n8) {
    int i = blockIdx.x * 256 + threadIdx.x;
    if (i >= n8) return;
    float4 a = ((const float4*)X)[2 * i];
    float4 b = ((const float4*)X)[2 * i + 1];
    u16x8 p;
    p[0] = f2bf(a.x); p[1] = f2bf(a.y); p[2] = f2bf(a.z); p[3] = f2bf(a.w);
    p[4] = f2bf(b.x); p[5] = f2bf(b.y); p[6] = f2bf(b.z); p[7] = f2bf(b.w);
    ((u16x8*)Y)[i] = p;
}

// Fold Wx against ax_dst: wv[h*768+f] = sum_d Wx[h][f][d]*ax[h][96+d];
// cd[h] = sum_d bx[h][d]*ax[h][96+d]
__global__ void packWV(const float* __restrict__ Wx, const float* __restrict__ ax,
                       const float* __restrict__ bx,
                       float* __restrict__ wv, float* __restrict__ cd) {
    int idx = blockIdx.x * 256 + threadIdx.x;
    if (idx < 8 * 768) {
        int h = idx / 768, f = idx % 768;
        const float* wp = Wx + (size_t)h * 768 * HD + (size_t)f * HD;
        const float* ap = ax + h * 2 * HD + HD;
        float s = 0.f;
        for (int d = 0; d < HD; d++) s += wp[d] * ap[d];
        wv[idx] = s;
    }
    if (idx < 8) {
        const float* bp = bx + idx * HD;
        const float* ap = ax + idx * 2 * HD + HD;
        float s = 0.f;
        for (int d = 0; d < HD; d++) s += bp[d] * ap[d];
        cd[idx] = s;
    }
}

// ---------------------------------------------------------------------------
// Triple-source MFMA GEMM with f32 A (fused convert): 128x128, BK=32, 256 thr
// (4 waves 2x2), 4 blocks/CU. A: f32 global -> reg f2bf -> ds_write into
// double-buffered padded LDS (stride 40 bf16 = 80B). B: global_load_lds w=16,
// double-buffered, XOR source-preswizzle (slot s holds k-word s^((r>>1)&3)).
// One __syncthreads per K-step. XCD-aware tile swizzle. (round-13 proven)
// ---------------------------------------------------------------------------
__global__ __launch_bounds__(256, 4) void mgemm3s(
    const float* __restrict__ A1, const float* __restrict__ A2,
    const float* __restrict__ A3,
    const unsigned short* __restrict__ BT1, const unsigned short* __restrict__ BT2,
    const float* __restrict__ bias1, const float* __restrict__ bias2,
    unsigned short* __restrict__ C1, unsigned short* __restrict__ C2,
    unsigned short* __restrict__ C3,
    int mt1, int mt2, int N, int K) {
    __shared__ unsigned short Alds[2][128 * 40];   // 2 x 10240 B
    __shared__ unsigned short Blds[2][128 * 32];   // 2 x  8192 B
    const int tid = threadIdx.x;
    const int w = tid >> 6, l = tid & 63;
    const int wr = w >> 1, wc = w & 1;
    const int lrow = l & 15, lk = l >> 4;

    const int nx = gridDim.x;
    const int nwg = nx * gridDim.y;
    int lin = blockIdx.y * nx + blockIdx.x;
    if ((nwg & 7) == 0) lin = (lin & 7) * (nwg >> 3) + (lin >> 3);
    int bm = lin / nx;
    const int bn = lin % nx;

    const int part = (bm >= mt1) + (bm >= mt2);
    const float* A           = part == 0 ? A1 : (part == 1 ? A2 : A3);
    const unsigned short* BT = part == 0 ? BT1 : BT2;
    const float* bias        = part == 0 ? bias1 : bias2;
    unsigned short* C        = part == 0 ? C1 : (part == 1 ? C2 : C3);
    bm -= (part == 1 ? mt1 : (part == 2 ? mt2 : 0));

    const unsigned short* bsrc[2];
    #pragma unroll
    for (int q = 0; q < 2; q++) {
        int idx = q * 256 + tid;
        int r = idx >> 2, s = idx & 3;
        int kw = s ^ ((r >> 1) & 3);
        bsrc[q] = BT + (size_t)(bn * 128 + r) * K + kw * 8;
    }
    const int ldst = (w * 64) * 8;

    const int arow = tid >> 1;
    const int as0 = (tid & 1) * 2;
    const float* aptr = A + (size_t)(bm * 128 + arow) * K + as0 * 8;

    auto stageA = [&](int buf, int k0) {
        float4 a0 = *(const float4*)(aptr + k0);
        float4 a1 = *(const float4*)(aptr + k0 + 4);
        float4 a2 = *(const float4*)(aptr + k0 + 8);
        float4 a3 = *(const float4*)(aptr + k0 + 12);
        u16x8 p0, p1;
        p0[0] = f2bf(a0.x); p0[1] = f2bf(a0.y); p0[2] = f2bf(a0.z); p0[3] = f2bf(a0.w);
        p0[4] = f2bf(a1.x); p0[5] = f2bf(a1.y); p0[6] = f2bf(a1.z); p0[7] = f2bf(a1.w);
        p1[0] = f2bf(a2.x); p1[1] = f2bf(a2.y); p1[2] = f2bf(a2.z); p1[3] = f2bf(a2.w);
        p1[4] = f2bf(a3.x); p1[5] = f2bf(a3.y); p1[6] = f2bf(a3.z); p1[7] = f2bf(a3.w);
        *(u16x8*)(&Alds[buf][arow * 40 + as0 * 8]) = p0;
        *(u16x8*)(&Alds[buf][arow * 40 + as0 * 8 + 8]) = p1;
    };

    gload_lds16(bsrc[0], &Blds[0][ldst]);
    gload_lds16(bsrc[1], &Blds[0][2048 + ldst]);
    stageA(0, 0);

    f32x4 acc[4][4] = {};
    const int nt = K >> 5;

    for (int t = 0; t < nt; ++t) {
        const int cur = t & 1;
        __syncthreads();
        if (t + 1 < nt) {
            const int k1 = (t + 1) << 5;
            gload_lds16(bsrc[0] + k1, &Blds[cur ^ 1][ldst]);
            gload_lds16(bsrc[1] + k1, &Blds[cur ^ 1][2048 + ldst]);
            stageA(cur ^ 1, k1);
        }
        bf16x8 af[4], bfv[4];
        #pragma unroll
        for (int i = 0; i < 4; i++) {
            int r = wr * 64 + i * 16 + lrow;
            af[i] = *(const bf16x8*)(&Alds[cur][r * 40 + lk * 8]);
        }
        #pragma unroll
        for (int j = 0; j < 4; j++) {
            int r = wc * 64 + j * 16 + lrow;
            int s = lk ^ ((r >> 1) & 3);
            bfv[j] = *(const bf16x8*)(&Blds[cur][r * 32 + s * 8]);
        }
        #pragma unroll
        for (int i = 0; i < 4; i++)
            #pragma unroll
            for (int j = 0; j < 4; j++)
                acc[i][j] = __builtin_amdgcn_mfma_f32_16x16x32_bf16(af[i], bfv[j], acc[i][j], 0, 0, 0);
    }

    const size_t crow0 = (size_t)bm * 128 + wr * 64;
    const int ccol0 = bn * 128 + wc * 64;
    #pragma unroll
    for (int j = 0; j < 4; j++) {
        int col = ccol0 + j * 16 + lrow;
        float bv = bias[col];
        #pragma unroll
        for (int i = 0; i < 4; i++) {
            size_t row = crow0 + i * 16 + lk * 4;
            #pragma unroll
            for (int e = 0; e < 4; e++)
                C[(row + e) * N + col] = f2bf(acc[i][j][e] + bv);
        }
    }
}

// ---------------------------------------------------------------------------
// Dual-source bf16 MFMA GEMM (round-10 proven): 128x128, BK=32, 4 blocks/CU,
// dbuf LDS, one barrier per K-step, XOR preswizzle, XCD swizzle. GRU GEMMs.
// ---------------------------------------------------------------------------
__global__ __launch_bounds__(256, 4) void mgemm2(
    const unsigned short* __restrict__ A1, const unsigned short* __restrict__ A2,
    const unsigned short* __restrict__ BT1, const unsigned short* __restrict__ BT2,
    const float* __restrict__ bias1, const float* __restrict__ bias2,
    unsigned short* __restrict__ C1, unsigned short* __restrict__ C2,
    int mt1, int N, int K) {
    __shared__ unsigned short Alds[2][128 * 32];
    __shared__ unsigned short Blds[2][128 * 32];
    const int tid = threadIdx.x;
    const int w = tid >> 6, l = tid & 63;
    const int wr = w >> 1, wc = w & 1;
    const int lrow = l & 15, lk = l >> 4;

    const int nx = gridDim.x;
    const int nwg = nx * gridDim.y;
    int lin = blockIdx.y * nx + blockIdx.x;
    if ((nwg & 7) == 0) lin = (lin & 7) * (nwg >> 3) + (lin >> 3);
    int bm = lin / nx;
    const int bn = lin % nx;

    const bool p1 = bm < mt1;
    const unsigned short* A  = p1 ? A1 : A2;
    const unsigned short* BT = p1 ? BT1 : BT2;
    const float* bias        = p1 ? bias1 : bias2;
    unsigned short* C        = p1 ? C1 : C2;
    if (!p1) bm -= mt1;

    const unsigned short* asrc[2];
    const unsigned short* bsrc[2];
    #pragma unroll
    for (int q = 0; q < 2; q++) {
        int idx = q * 256 + tid;
        int r = idx >> 2, s = idx & 3;
        int kw = s ^ ((r >> 1) & 3);
        asrc[q] = A  + (size_t)(bm * 128 + r) * K + kw * 8;
        bsrc[q] = BT + (size_t)(bn * 128 + r) * K + kw * 8;
    }
    const int ldst = (w * 64) * 8;

    gload_lds16(asrc[0], &Alds[0][ldst]);
    gload_lds16(asrc[1], &Alds[0][2048 + ldst]);
    gload_lds16(bsrc[0], &Blds[0][ldst]);
    gload_lds16(bsrc[1], &Blds[0][2048 + ldst]);

    f32x4 acc[4][4] = {};
    const int nt = K >> 5;

    for (int t = 0; t < nt; ++t) {
        const int cur = t & 1;
        __syncthreads();
        if (t + 1 < nt) {
            const int k1 = (t + 1) << 5;
            gload_lds16(asrc[0] + k1, &Alds[cur ^ 1][ldst]);
            gload_lds16(asrc[1] + k1, &Alds[cur ^ 1][2048 + ldst]);
            gload_lds16(bsrc[0] + k1, &Blds[cur ^ 1][ldst]);
            gload_lds16(bsrc[1] + k1, &Blds[cur ^ 1][2048 + ldst]);
        }
        bf16x8 af[4], bfv[4];
        #pragma unroll
        for (int i = 0; i < 4; i++) {
            int r = wr * 64 + i * 16 + lrow;
            int s = lk ^ ((r >> 1) & 3);
            af[i] = *(const bf16x8*)(&Alds[cur][r * 32 + s * 8]);
        }
        #pragma unroll
        for (int j = 0; j < 4; j++) {
            int r = wc * 64 + j * 16 + lrow;
            int s = lk ^ ((r >> 1) & 3);
            bfv[j] = *(const bf16x8*)(&Blds[cur][r * 32 + s * 8]);
        }
        #pragma unroll
        for (int i = 0; i < 4; i++)
            #pragma unroll
            for (int j = 0; j < 4; j++)
                acc[i][j] = __builtin_amdgcn_mfma_f32_16x16x32_bf16(af[i], bfv[j], acc[i][j], 0, 0, 0);
    }

    const size_t crow0 = (size_t)bm * 128 + wr * 64;
    const int ccol0 = bn * 128 + wc * 64;
    #pragma unroll
    for (int j = 0; j < 4; j++) {
        int col = ccol0 + j * 16 + lrow;
        float bv = bias[col];
        #pragma unroll
        for (int i = 0; i < 4; i++) {
            size_t row = crow0 + i * 16 + lk * 4;
            #pragma unroll
            for (int e = 0; e < 4; e++)
                C[(row + e) * N + col] = f2bf(acc[i][j][e] + bv);
        }
    }
}

// ---------------------------------------------------------------------------
// Fused dual edge score (intra): both halves in one pass over X.
// ---------------------------------------------------------------------------
__global__ __launch_bounds__(256) void escore2(
    const unsigned short* __restrict__ X, const float* __restrict__ a,
    float* __restrict__ s0out, float* __restrict__ s1out) {
    __shared__ float av0[768], av1[768];
    for (int t = threadIdx.x; t < 768; t += 256) {
        int hh = t / HD, d = t % HD;
        av0[t] = a[hh * 2 * HD + d];
        av1[t] = a[hh * 2 * HD + HD + d];
    }
    __syncthreads();
    int idx = blockIdx.x * 256 + threadIdx.x;   // (n,h)
    int row = idx >> 3, hh = idx & 7;
    const unsigned short* xp = X + (size_t)row * 768 + hh * HD;
    const float* a0 = av0 + hh * HD;
    const float* a1 = av1 + hh * HD;
    float s0 = 0.f, s1 = 0.f;
    #pragma unroll
    for (int q = 0; q < 12; q++) {
        u16x8 v = *(const u16x8*)(xp + q * 8);
        #pragma unroll
        for (int e = 0; e < 8; e++) {
            float x = bf2f(v[e]);
            s0 += x * a0[q * 8 + e];
            s1 += x * a1[q * 8 + e];
        }
    }
    s0out[idx] = s0;
    s1out[idx] = s1;
}

// single-half edge score (src scores for the merged counter/support table)
__global__ __launch_bounds__(256) void escore(
    const unsigned short* __restrict__ X, const float* __restrict__ a,
    int half, float* __restrict__ sc) {
    __shared__ float av[768];
    for (int t = threadIdx.x; t < 768; t += 256) {
        int hh = t / HD, d = t % HD;
        av[t] = a[hh * 2 * HD + half * HD + d];
    }
    __syncthreads();
    int idx = blockIdx.x * 256 + threadIdx.x;
    int row = idx >> 3, hh = idx & 7;
    const unsigned short* xp = X + (size_t)row * 768 + hh * HD;
    const float* ap = av + hh * HD;
    float s = 0.f;
    #pragma unroll
    for (int q = 0; q < 12; q++) {
        u16x8 v = *(const u16x8*)(xp + q * 8);
        #pragma unroll
        for (int e = 0; e < 8; e++) s += bf2f(v[e]) * ap[q * 8 + e];
    }
    sc[idx] = s;
}

// ---------------------------------------------------------------------------
// Folded dst-score: ED[n,h] = sum_f X[n,f]*wv[h,f] + cd[h].
// ---------------------------------------------------------------------------
__global__ __launch_bounds__(256) void escore_fold(
    const unsigned short* __restrict__ X, const float* __restrict__ wv,
    const float* __restrict__ cd, float* __restrict__ ed) {
    __shared__ float wvs[8][8][97];
    __shared__ float cds[8];
    for (int i = threadIdx.x; i < 8 * 8 * 96; i += 256) {
        int j = i / (8 * 96); int r = i % (8 * 96); int h = r / 96; int t = r % 96;
        wvs[j][h][t] = wv[h * 768 + j * 96 + t];
    }
    if (threadIdx.x < 8) cds[threadIdx.x] = cd[threadIdx.x];
    __syncthreads();
    int idx = blockIdx.x * 256 + threadIdx.x;
    int n = idx >> 3, j = idx & 7;
    const unsigned short* xp = X + (size_t)n * 768 + j * 96;
    float p[8] = {};
    #pragma unroll
    for (int q = 0; q < 12; q++) {
        u16x8 v = *(const u16x8*)(xp + q * 8);
        #pragma unroll
        for (int e = 0; e < 8; e++) {
            float x = bf2f(v[e]);
            #pragma unroll
            for (int h = 0; h < 8; h++) p[h] += x * wvs[j][h][q * 8 + e];
        }
    }
    #pragma unroll
    for (int o = 1; o < 8; o <<= 1)
        #pragma unroll
        for (int h = 0; h < 8; h++) p[h] += __shfl_xor(p[h], o, 64);
    ed[(size_t)n * 8 + j] = p[j] + cds[j];
}

// ---------------------------------------------------------------------------
// Per-dst softmax + aggregate, one WAVE per dst segment. (intra branch)
// ---------------------------------------------------------------------------
__global__ __launch_bounds__(256) void attend_agg(
    const unsigned short* __restrict__ Whs, const float* __restrict__ es,
    const float* __restrict__ ed, const float* __restrict__ ab,
    const int* __restrict__ src, const int* __restrict__ dst,
    unsigned short* __restrict__ out) {
    const int wv = threadIdx.x >> 6, l = threadIdx.x & 63;
    const int seg = blockIdx.x * 4 + wv;
    const int hh = l >> 3, j = l & 7;
    int sj = src[seg * 8 + j];
    int dnode = dst[seg * 8];
    float e = es[(size_t)sj * 8 + hh] + ed[(size_t)dnode * 8 + hh] + ab[hh];
    e = e > 0.f ? e : LRELU_ALPHA * e;
    float m = e;
    #pragma unroll
    for (int o = 1; o < 8; o <<= 1) m = fmaxf(m, __shfl_xor(m, o, 64));
    float ex = expf(e - m);
    float s = ex;
    #pragma unroll
    for (int o = 1; o < 8; o <<= 1) s += __shfl_xor(s, o, 64);
    float att = ex / s;

    #pragma unroll
    for (int u = 0; u < 3; u++) {
        int c = 4 * l + 256 * u;
        int h = c / HD;
        float acc0 = 0.f, acc1 = 0.f, acc2 = 0.f, acc3 = 0.f;
        #pragma unroll
        for (int j2 = 0; j2 < 8; j2++) {
            float a = __shfl(att, h * 8 + j2, 64);
            int sid = __shfl(sj, j2, 64);
            u16x4 v = *(const u16x4*)(Whs + (size_t)sid * 768 + c);
            acc0 += a * bf2f(v[0]); acc1 += a * bf2f(v[1]);
            acc2 += a * bf2f(v[2]); acc3 += a * bf2f(v[3]);
        }
        u16x4 r;
        r[0] = f2bf(acc0); r[1] = f2bf(acc1); r[2] = f2bf(acc2); r[3] = f2bf(acc3);
        *(u16x4*)(out + (size_t)dnode * 768 + c) = r;
    }
}

// ---------------------------------------------------------------------------
// Fused counter+support attend: Hd = 0.5*attend(Wc, esC) + 0.5*attend(Ws, esS).
// ---------------------------------------------------------------------------
__global__ __launch_bounds__(256) void attend2(
    const unsigned short* __restrict__ Wc, const unsigned short* __restrict__ Ws,
    const float* __restrict__ esC, const float* __restrict__ esS,
    const float* __restrict__ ed, const float* __restrict__ ab,
    const int* __restrict__ csrc, const int* __restrict__ ssrc,
    const int* __restrict__ dst, unsigned short* __restrict__ outH) {
    const int wv = threadIdx.x >> 6, l = threadIdx.x & 63;
    const int seg = blockIdx.x * 4 + wv;
    const int hh = l >> 3, j = l & 7;
    int cj = csrc[seg * 8 + j];
    int sj = ssrc[seg * 8 + j];
    int dnode = dst[seg * 8];
    float edv = ed[(size_t)dnode * 8 + hh] + ab[hh];

    float eC = esC[(size_t)cj * 8 + hh] + edv;
    eC = eC > 0.f ? eC : LRELU_ALPHA * eC;
    float mC = eC;
    #pragma unroll
    for (int o = 1; o < 8; o <<= 1) mC = fmaxf(mC, __shfl_xor(mC, o, 64));
    float exC = expf(eC - mC);
    float sC = exC;
    #pragma unroll
    for (int o = 1; o < 8; o <<= 1) sC += __shfl_xor(sC, o, 64);
    float attC = exC / sC;

    float eS = esS[(size_t)sj * 8 + hh] + edv;
    eS = eS > 0.f ? eS : LRELU_ALPHA * eS;
    float mS = eS;
    #pragma unroll
    for (int o = 1; o < 8; o <<= 1) mS = fmaxf(mS, __shfl_xor(mS, o, 64));
    float exS = expf(eS - mS);
    float sS = exS;
    #pragma unroll
    for (int o = 1; o < 8; o <<= 1) sS += __shfl_xor(sS, o, 64);
    float attS = exS / sS;

    #pragma unroll
    for (int u = 0; u < 3; u++) {
        int c = 4 * l + 256 * u;
        int h = c / HD;
        float acc0 = 0.f, acc1 = 0.f, acc2 = 0.f, acc3 = 0.f;
        #pragma unroll
        for (int j2 = 0; j2 < 8; j2++) {
            float a = __shfl(attC, h * 8 + j2, 64);
            int sid = __shfl(cj, j2, 64);
            u16x4 v = *(const u16x4*)(Wc + (size_t)sid * 768 + c);
            acc0 += a * bf2f(v[0]); acc1 += a * bf2f(v[1]);
            acc2 += a * bf2f(v[2]); acc3 += a * bf2f(v[3]);
        }
        #pragma unroll
        for (int j2 = 0; j2 < 8; j2++) {
            float a = __shfl(attS, h * 8 + j2, 64);
            int sid = __shfl(sj, j2, 64);
            u16x4 v = *(const u16x4*)(Ws + (size_t)sid * 768 + c);
            acc0 += a * bf2f(v[0]); acc1 += a * bf2f(v[1]);
            acc2 += a * bf2f(v[2]); acc3 += a * bf2f(v[3]);
        }
        u16x4 r;
        r[0] = f2bf(0.5f * acc0); r[1] = f2bf(0.5f * acc1);
        r[2] = f2bf(0.5f * acc2); r[3] = f2bf(0.5f * acc3);
        *(u16x4*)(outH + (size_t)dnode * 768 + c) = r;
    }
}

// ---------------------------------------------------------------------------
// GRU elementwise tail (bf16 gi/gh/hid, f32 out), 8 cols/thread.
// ---------------------------------------------------------------------------
__global__ __launch_bounds__(256) void gru_elem(
    const unsigned short* __restrict__ gi, const unsigned short* __restrict__ gh,
    const unsigned short* __restrict__ hid, float* __restrict__ out) {
    int idx = blockIdx.x * 256 + threadIdx.x;   // over rows*96
    int nrow = idx / 96, c8 = (idx % 96) * 8;
    const unsigned short* gip = gi + (size_t)nrow * 2304 + c8;
    const unsigned short* ghp = gh + (size_t)nrow * 2304 + c8;
    u16x8 vir = *(const u16x8*)(gip);
    u16x8 viz = *(const u16x8*)(gip + 768);
    u16x8 vin = *(const u16x8*)(gip + 1536);
    u16x8 vhr = *(const u16x8*)(ghp);
    u16x8 vhz = *(const u16x8*)(ghp + 768);
    u16x8 vhn = *(const u16x8*)(ghp + 1536);
    u16x8 vh  = *(const u16x8*)(hid + (size_t)nrow * 768 + c8);
    float res[8];
    #pragma unroll
    for (int e = 0; e < 8; e++) {
        float r = 1.f / (1.f + expf(-(bf2f(vir[e]) + bf2f(vhr[e]))));
        float z = 1.f / (1.f + expf(-(bf2f(viz[e]) + bf2f(vhz[e]))));
        float cand = tanhf(bf2f(vin[e]) + r * bf2f(vhn[e]));
        res[e] = (1.f - z) * cand + z * bf2f(vh[e]);
    }
    float* op = out + (size_t)nrow * 768 + c8;
    *(float4*)(op)     = make_float4(res[0], res[1], res[2], res[3]);
    *(float4*)(op + 4) = make_float4(res[4], res[5], res[6], res[7]);
}

// ---------------------------------------------------------------------------
// Launch (round-13 best-known configuration, 904.7 us).
// ws (bf16 elems): Xb[SZ] | Hdb[SZ] | GIb[CH*2304] | GHb[CH*2304] |
//   W2gT W2xT WihB WhhB | f32: EScat[2NE] ED ESI EDI wv cd.
// Pcat ([2NT,768] bf16 proj scratch) = d_out. Wh lives in Hdb until attend2.
// ---------------------------------------------------------------------------
extern "C" void kernel_launch(void* const* d_in, const int* in_sizes, int n_in,
                              void* d_out, int out_size, void* d_ws, size_t ws_size,
                              hipStream_t stream) {
    const float* h    = (const float*)d_in[0];
    const float* hbc  = (const float*)d_in[1];
    const float* hbs  = (const float*)d_in[2];
    const float* Wg   = (const float*)d_in[3];
    const float* bg   = (const float*)d_in[4];
    const float* ag   = (const float*)d_in[5];
    const float* agb  = (const float*)d_in[6];
    const float* Wx   = (const float*)d_in[7];
    const float* bx   = (const float*)d_in[8];
    const float* ax   = (const float*)d_in[9];
    const float* axb  = (const float*)d_in[10];
    const float* Wih  = (const float*)d_in[11];
    const float* Whh  = (const float*)d_in[12];
    const float* bih  = (const float*)d_in[13];
    const float* bhh  = (const float*)d_in[14];
    const int* i_src  = (const int*)d_in[15];
    const int* i_dst  = (const int*)d_in[16];
    const int* c_src  = (const int*)d_in[17];
    const int* c_dst  = (const int*)d_in[18];
    const int* s_src  = (const int*)d_in[19];
    const int* s_dst  = (const int*)d_in[20];
    float* out = (float*)d_out;

    const size_t SZ = (size_t)NT * 768;
    unsigned short* Xb   = (unsigned short*)d_ws;
    unsigned short* Hdb  = Xb + SZ;
    unsigned short* GIb  = Hdb + SZ;
    unsigned short* GHb  = GIb + (size_t)CH * 2304;
    unsigned short* W2gT = GHb + (size_t)CH * 2304;
    unsigned short* W2xT = W2gT + 768 * 768;
    unsigned short* WihB = W2xT + 768 * 768;
    unsigned short* WhhB = WihB + 2304 * 768;
    float* EScat = (float*)(WhhB + 2304 * 768);      // [2NE]
    float* ED    = EScat + 2 * NE;
    float* ESI   = ED + NE;
    float* EDI   = ESI + NE;
    float* WV    = EDI + NE;                         // [8*768]
    float* CD    = WV + 8 * 768;                     // [8]
    unsigned short* Pcat = (unsigned short*)d_out;   // [2NT,768] bf16 scratch

    dim3 blk(256);
    packWT<<<(768 * 768 + 255) / 256, blk, 0, stream>>>(Wg, W2gT);
    packWT<<<(768 * 768 + 255) / 256, blk, 0, stream>>>(Wx, W2xT);
    cvt_bf8<<<(2304 * 768 / 8 + 255) / 256, blk, 0, stream>>>(Wih, WihB, 2304 * 768 / 8);
    cvt_bf8<<<(2304 * 768 / 8 + 255) / 256, blk, 0, stream>>>(Whh, WhhB, 2304 * 768 / 8);
    packWV<<<(8 * 768 + 255) / 256, blk, 0, stream>>>(Wx, ax, bx, WV, CD);

    // 1) merged projection GEMM (one dispatch, 4608 wg, f32 A reg-staged):
    //    part1 (256 tiles): Wh = h@Wg+bg -> Hdb
    //    part2 (256 tiles): Wc = hbc@Wx+bx -> Pcat[0:NT]
    //    part3 (256 tiles): Ws = hbs@Wx+bx -> Pcat[NT:2NT]
    dim3 gproj(6, 768);
    mgemm3s<<<gproj, blk, 0, stream>>>(h, hbc, hbs, W2gT, W2xT, bg, bx,
                                       Hdb, Pcat, Pcat + SZ, 256, 512, 768, 768);
    // 2) intra: dual scores over Wh (in Hdb), attend -> Xb
    escore2<<<NE / 256, blk, 0, stream>>>(Hdb, ag, ESI, EDI);
    attend_agg<<<NT / 4, blk, 0, stream>>>(Hdb, ESI, EDI, agb, i_src, i_dst, Xb);
    // 3) folded dst scores: ED = Xb @ wv^T + cd
    escore_fold<<<NE / 256, blk, 0, stream>>>(Xb, WV, CD, ED);
    // 4) src scores over merged [Wc;Ws] table
    escore<<<2 * NE / 256, blk, 0, stream>>>(Pcat, ax, 0, EScat);
    // 5) fused counter+support attend -> Hdb (Wh dead now)
    attend2<<<NT / 4, blk, 0, stream>>>(Pcat, Pcat + SZ, EScat, EScat + NE, ED, axb,
                                        c_src, s_src, c_dst, Hdb);
    // 6) GRU, row-chunked; gi/gh as ONE dual-source dispatch per chunk
    dim3 ggru(18, 256);
    for (int c0 = 0; c0 < NT; c0 += CH) {
        mgemm2<<<ggru, blk, 0, stream>>>(Xb + (size_t)c0 * 768, Hdb + (size_t)c0 * 768,
                                         WihB, WhhB, bih, bhh, GIb, GHb,
                                         128, 2304, 768);
        gru_elem<<<(CH * 96) / 256, blk, 0, stream>>>(GIb, GHb, Hdb + (size_t)c0 * 768, out + (size_t)c0 * 768);
    }
}